// Round 5
// baseline (273.435 us; speedup 1.0000x reference)
//
#include <hip/hip_runtime.h>
#include <math.h>

typedef unsigned short ushort_t;
typedef __bf16 bf16x8 __attribute__((ext_vector_type(8)));
typedef ushort_t ushort8v __attribute__((ext_vector_type(8)));
typedef float f32x4 __attribute__((ext_vector_type(4)));

#define B_SZ   4
#define SEQ    8192
#define M_ROWS (B_SZ * SEQ)   // 32768
#define CH     128
#define NC     (SEQ / CH)     // 64

__device__ __forceinline__ ushort_t f2bf(float f) {
    unsigned u = __float_as_uint(f);
    u = u + 0x7fffu + ((u >> 16) & 1u);
    return (ushort_t)(u >> 16);
}
__device__ __forceinline__ float bf2f(ushort_t b) {
    return __uint_as_float(((unsigned)b) << 16);
}

__device__ __forceinline__ void load16_lds(const void* g, void* l) {
    __builtin_amdgcn_global_load_lds(
        (const __attribute__((address_space(1))) unsigned int*)g,
        (__attribute__((address_space(3))) unsigned int*)l, 16, 0, 0);
}

__device__ __forceinline__ bf16x8 ldfrag(const ushort_t* p) {
    union { ushort8v u; bf16x8 b; } cv;
    cv.u = *(const ushort8v*)p;
    return cv.b;
}

__device__ __forceinline__ float2 cmul(float2 a, float2 b) {
    return make_float2(a.x * b.x - a.y * b.y, a.x * b.y + a.y * b.x);
}

// ---------------------------------------------------------------------------
// prepconv: conv_x (all 16384 blocks) + prep (blocks < 1024) in ONE dispatch.
__global__ void prepconv_kernel(const float* __restrict__ x,
                                ushort_t* __restrict__ X16,
                                const float* __restrict__ Lre,
                                const float* __restrict__ Lim,
                                const float* __restrict__ ldt,
                                const float* __restrict__ Bre,
                                const float* __restrict__ Bim,
                                const float* __restrict__ Cre,
                                const float* __restrict__ Cim,
                                float* __restrict__ abar,
                                float* __restrict__ apow,
                                float* __restrict__ PW,
                                ushort_t* __restrict__ Bmat,
                                ushort_t* __restrict__ Cmat) {
    int i = blockIdx.x * 256 + threadIdx.x;
    float4 v = ((const float4*)x)[i];
    ushort_t o[4] = {f2bf(v.x), f2bf(v.y), f2bf(v.z), f2bf(v.w)};
    *(uint2*)&X16[(size_t)i * 4] = *(const uint2*)o;

    if (blockIdx.x < 1024) {
        int idx = i;                        // 0 .. 262143
        int h = idx & 511;
        int p = (idx >> 9) & 255;
        int d = idx >> 17;
        int ip = d * 256 + p;
        float lr = Lre[ip], li = Lim[ip];
        float dt = expf(ldt[ip]);
        float e   = expf(lr * dt);
        float ang = li * dt;
        float ar = e * cosf(ang), ai = e * sinf(ang);
        float nr = ar - 1.0f, ni = ai;
        float den = lr * lr + li * li;
        float cr = (nr * lr + ni * li) / den;
        float ci = (ni * lr - nr * li) / den;
        float br = Bre[idx], bi = Bim[idx];
        Bmat[(d * 512 + 2 * p) * 512 + h]     = f2bf(cr * br - ci * bi);
        Bmat[(d * 512 + 2 * p + 1) * 512 + h] = f2bf(cr * bi + ci * br);
        if (h == 0) {
            int oo = d * 512 + 2 * p;
            abar[oo] = ar;  abar[oo + 1] = ai;
            float eC = expf(lr * dt * (float)CH);
            float aC = ang * (float)CH;
            apow[oo] = eC * cosf(aC);  apow[oo + 1] = eC * sinf(aC);
            float2 a1 = make_float2(ar, ai);
            float2 a2 = cmul(a1, a1);
            float2 a4 = cmul(a2, a2);
            float2 a8 = cmul(a4, a4);
            float2 a16 = cmul(a8, a8);
            int q = d * 256 + p;
            PW[q * 6 + 0] = a1.x;  PW[q * 6 + 1] = a1.y;
            PW[q * 6 + 2] = a4.x;  PW[q * 6 + 3] = a4.y;
            PW[q * 6 + 4] = a16.x; PW[q * 6 + 5] = a16.y;
        }
        int p2 = idx & 255;
        int h2 = (idx >> 8) & 511;
        int d2 = idx >> 17;
        Cmat[h2 * 1024 + d2 * 512 + 2 * p2]     = f2bf(Cre[idx]);
        Cmat[h2 * 1024 + d2 * 512 + 2 * p2 + 1] = f2bf(-Cim[idx]);
    }
}

// ---------------------------------------------------------------------------
// 256x256 8-phase bf16 GEMM (T2+T3+T4+T5), Round-1 loop structure.
// NEW this round: coalesced epilogue.  Per mi, each wave transposes its
// 16x64 output patch through a wave-private LDS region (row stride padded to
// 144B bf16 / 272B f32: 16B-aligned, <=2-way bank alias), then stores
// dwordx4 (128B-line coalesced).  EPI==1 additionally reads X and Dv with
// coalesced float4 loads (Dv hoisted out of the mi loop).
// One lgkmcnt(0)+s_barrier after the K-loop before reusing shA as scratch.
template<int EPI, int KD_, int NT>
__global__ __launch_bounds__(512, 2)
void gemm_8ph(const ushort_t* __restrict__ A, const ushort_t* __restrict__ Bm,
              ushort_t* __restrict__ Cb, float* __restrict__ Cf,
              const float* __restrict__ X, const float* __restrict__ Dv,
              const float* __restrict__ PW, float* __restrict__ CAR) {
    __shared__ ushort_t shA[2][2][256 * 32];
    __shared__ ushort_t shB[2][2][256 * 32];
    constexpr int NKT = KD_ / 64;

    const int tid  = threadIdx.x;
    const int lane = tid & 63;
    const int wv   = tid >> 6;
    const int wr = wv >> 2, wc = wv & 3;
    const int l15 = lane & 15, lq = lane >> 4;

    const int lin = blockIdx.x;
    const int xcd = lin & 7;
    const int j   = lin >> 3;
    const int mt  = xcd * 16 + j / NT;
    const int nt  = j % NT;
    const int m0 = mt * 256;
    const int n0 = nt * 256;
    const int CN = NT * 256;

    f32x4 acc[8][4];
#pragma unroll
    for (int i = 0; i < 8; ++i)
#pragma unroll
        for (int jj = 0; jj < 4; ++jj)
            acc[i][jj] = (f32x4){0.f, 0.f, 0.f, 0.f};

    const int srow = wv * 32 + (lane >> 2);
    const int sck  = (((lane & 3) ^ ((lane >> 3) & 3))) * 8;
    const ushort_t* Ag = A  + (size_t)(m0 + srow) * KD_ + sck;
    const ushort_t* Bg = Bm + (size_t)(n0 + srow) * KD_ + sck;

#define STAGE_A(t, ks) do {                                                   \
        const ushort_t* g_ = Ag + (size_t)(t) * 64 + (ks) * 32;               \
        ushort_t* d_ = &shA[(t) & 1][(ks)][wv * 1024];                        \
        load16_lds(g_, d_);                                                   \
        load16_lds(g_ + (size_t)16 * KD_, d_ + 512);                          \
    } while (0)
#define STAGE_B(t, ks) do {                                                   \
        const ushort_t* g_ = Bg + (size_t)(t) * 64 + (ks) * 32;               \
        ushort_t* d_ = &shB[(t) & 1][(ks)][wv * 1024];                        \
        load16_lds(g_, d_);                                                   \
        load16_lds(g_ + (size_t)16 * KD_, d_ + 512);                          \
    } while (0)

    const int rdoff = ((lq ^ ((l15 >> 1) & 3))) * 8;
    const int rdA = (wr * 128 + l15) * 32 + rdoff;
    const int rdB = (wc * 64  + l15) * 32 + rdoff;

#define MFMA_PH(bx, by, nlo) do {                                             \
        __builtin_amdgcn_s_setprio(1);                                        \
        _Pragma("unroll")                                                     \
        for (int mi_ = 0; mi_ < 8; ++mi_) {                                   \
            acc[mi_][nlo]     = __builtin_amdgcn_mfma_f32_16x16x32_bf16(      \
                af[mi_], bx, acc[mi_][nlo], 0, 0, 0);                         \
            acc[mi_][nlo + 1] = __builtin_amdgcn_mfma_f32_16x16x32_bf16(      \
                af[mi_], by, acc[mi_][nlo + 1], 0, 0, 0);                     \
        }                                                                     \
        __builtin_amdgcn_s_setprio(0);                                        \
    } while (0)

    STAGE_A(0, 0); STAGE_A(0, 1); STAGE_B(0, 0); STAGE_B(0, 1);
    STAGE_A(1, 0); STAGE_B(1, 0); STAGE_A(1, 1);
    asm volatile("s_waitcnt vmcnt(6)" ::: "memory");
    __builtin_amdgcn_s_barrier();

    bf16x8 af[8];
#pragma unroll 2
    for (int kt = 0; kt < NKT; ++kt) {
        const int buf = kt & 1;
        const ushort_t* aS0 = &shA[buf][0][rdA];
        const ushort_t* aS1 = &shA[buf][1][rdA];
        const ushort_t* bS0 = &shB[buf][0][rdB];
        const ushort_t* bS1 = &shB[buf][1][rdB];

        { // phase 1: ks0 x ni{0,1}
#pragma unroll
            for (int mi = 0; mi < 8; ++mi) af[mi] = ldfrag(aS0 + mi * 512);
            bf16x8 b0 = ldfrag(bS0), b1 = ldfrag(bS0 + 512);
            if (kt + 1 < NKT) STAGE_B(kt + 1, 1);
            __builtin_amdgcn_s_barrier();
            MFMA_PH(b0, b1, 0);
            __builtin_amdgcn_s_barrier();
        }
        { // phase 2: ks0 x ni{2,3}
            bf16x8 b2 = ldfrag(bS0 + 1024), b3 = ldfrag(bS0 + 1536);
            if (kt + 2 < NKT) STAGE_A(kt + 2, 0);
            __builtin_amdgcn_s_barrier();
            MFMA_PH(b2, b3, 2);
            __builtin_amdgcn_s_barrier();
        }
        { // phase 3: ks1 x ni{0,1}
#pragma unroll
            for (int mi = 0; mi < 8; ++mi) af[mi] = ldfrag(aS1 + mi * 512);
            bf16x8 b0 = ldfrag(bS1), b1 = ldfrag(bS1 + 512);
            if (kt + 2 < NKT) STAGE_B(kt + 2, 0);
            __builtin_amdgcn_s_barrier();
            MFMA_PH(b0, b1, 0);
            __builtin_amdgcn_s_barrier();
        }
        { // phase 4: ks1 x ni{2,3} + tile boundary
            bf16x8 b2 = ldfrag(bS1 + 1024), b3 = ldfrag(bS1 + 1536);
            if (kt + 2 < NKT) STAGE_A(kt + 2, 1);
            __builtin_amdgcn_s_barrier();
            MFMA_PH(b2, b3, 2);
            if (kt + 1 < NKT) {
                if (kt + 2 < NKT)
                    asm volatile("s_waitcnt vmcnt(6)" ::: "memory");
                else
                    asm volatile("s_waitcnt vmcnt(0)" ::: "memory");
                __builtin_amdgcn_s_barrier();
            }
        }
    }
#undef STAGE_A
#undef STAGE_B
#undef MFMA_PH

    // ---- make shA safe to reuse as epilogue scratch ----
    asm volatile("s_waitcnt lgkmcnt(0)" ::: "memory");
    __builtin_amdgcn_s_barrier();

    const int rr = lane >> 2;            // epilogue store row within 16
    const int cc = (lane & 3) * 16;      // epilogue store col chunk (16 cols)

    if (EPI == 0) {
        // bf16 patch: [16][72] ushorts (144B row stride, 16B-mult)
        ushort_t* ep = (ushort_t*)((char*)shA + wv * 2304);
#pragma unroll
        for (int mi = 0; mi < 8; ++mi) {
#pragma unroll
            for (int ni = 0; ni < 4; ++ni)
#pragma unroll
                for (int r = 0; r < 4; ++r)
                    ep[(lq * 4 + r) * 72 + ni * 16 + l15] = f2bf(acc[mi][ni][r]);
            uint4 w0 = *(const uint4*)&ep[rr * 72 + cc];
            uint4 w1 = *(const uint4*)&ep[rr * 72 + cc + 8];
            const int rowg = m0 + wr * 128 + mi * 16 + rr;
            *(uint4*)&Cb[(size_t)rowg * CN + n0 + wc * 64 + cc]     = w0;
            *(uint4*)&Cb[(size_t)rowg * CN + n0 + wc * 64 + cc + 8] = w1;
        }
    } else {
        // f32 patch: [16][68] floats (272B row stride, 16B-mult)
        float* epf = (float*)((char*)shA + wv * 4352);
        const int colbase = n0 + wc * 64 + cc;
        f32x4 dsv[4];
#pragma unroll
        for (int j4 = 0; j4 < 4; ++j4)
            dsv[j4] = *(const f32x4*)&Dv[colbase + j4 * 4]
                    + *(const f32x4*)&Dv[512 + colbase + j4 * 4];
#pragma unroll
        for (int mi = 0; mi < 8; ++mi) {
#pragma unroll
            for (int ni = 0; ni < 4; ++ni)
#pragma unroll
                for (int r = 0; r < 4; ++r)
                    epf[(lq * 4 + r) * 68 + ni * 16 + l15] = acc[mi][ni][r];
            const int rowg = m0 + wr * 128 + mi * 16 + rr;
            const size_t gb = (size_t)rowg * 512 + colbase;
#pragma unroll
            for (int j4 = 0; j4 < 4; ++j4) {
                f32x4 v  = *(const f32x4*)&epf[rr * 68 + cc + j4 * 4];
                f32x4 xv = *(const f32x4*)&X[gb + j4 * 4];
                v = v + xv * dsv[j4];
                *(f32x4*)&Cf[gb + j4 * 4] = v;
            }
        }
    }

    // ---- fused chunk-carry (EPI==0 only), unchanged from Round 4 ----
    if (EPI == 0) {
        const int dirq = n0 >> 9;            // block-uniform
        const bool evn = ((l15 & 1) == 0);
        const int cidx = ((m0 >> 7) + wr) * 1024;

#define CACC(MI, R, CC) do {                                                  \
            float vo = bf2f(f2bf(acc[MI][ni][R]));                            \
            float vp = __shfl_xor(vo, 1);                                     \
            float vr = evn ? vo : vp;                                         \
            float vi = evn ? vp : vo;                                         \
            wr_ = fmaf(CC.x, vr, fmaf(-CC.y, vi, wr_));                       \
            wi_ = fmaf(CC.x, vi, fmaf(CC.y, vr, wi_));                        \
        } while (0)
#define CSTEP(MI) do {                                                        \
            float wr_ = 0.f, wi_ = 0.f;                                       \
            CACC(MI, 0, c0); CACC(MI, 1, c1);                                 \
            CACC(MI, 2, c2); CACC(MI, 3, c3);                                 \
            float comp = evn ? (t16.x * wr_ - t16.y * wi_)                    \
                             : (t16.x * wi_ + t16.y * wr_);                   \
            csum += comp;                                                     \
            t16 = cmul(t16, A16);                                             \
        } while (0)

#pragma unroll
        for (int ni = 0; ni < 4; ++ni) {
            const int col = n0 + wc * 64 + ni * 16 + l15;
            const int q = col >> 1;
            float2 A1  = make_float2(PW[q * 6 + 0], PW[q * 6 + 1]);
            float2 A4  = make_float2(PW[q * 6 + 2], PW[q * 6 + 3]);
            float2 A16 = make_float2(PW[q * 6 + 4], PW[q * 6 + 5]);
            const int lqp = dirq ? lq : 3 - lq;
            float2 A4_2 = cmul(A4, A4);
            float2 A4_3 = cmul(A4_2, A4);
            float2 P4 = (lqp == 0) ? make_float2(1.f, 0.f)
                       : (lqp == 1) ? A4
                       : (lqp == 2) ? A4_2 : A4_3;
            float2 c0, c1, c2, c3;
            if (dirq == 0) {
                c3 = P4; c2 = cmul(c3, A1); c1 = cmul(c2, A1); c0 = cmul(c1, A1);
            } else {
                c0 = P4; c1 = cmul(c0, A1); c2 = cmul(c1, A1); c3 = cmul(c2, A1);
            }
            float2 t16 = make_float2(1.f, 0.f);
            float csum = 0.f;
            if (dirq == 0) {
                CSTEP(7); CSTEP(6); CSTEP(5); CSTEP(4);
                CSTEP(3); CSTEP(2); CSTEP(1); CSTEP(0);
            } else {
                CSTEP(0); CSTEP(1); CSTEP(2); CSTEP(3);
                CSTEP(4); CSTEP(5); CSTEP(6); CSTEP(7);
            }
            csum += __shfl_xor(csum, 16);
            csum += __shfl_xor(csum, 32);
            if (lq == 0) CAR[cidx + col] = csum;
        }
#undef CACC
#undef CSTEP
    }
}

// ---------------------------------------------------------------------------
// scan_fin2 = scan_comb folded into scan_final (unchanged).
__global__ __launch_bounds__(512)
void scan_fin2(ushort_t* __restrict__ S, const float* __restrict__ abar,
               const float* __restrict__ apow, const float* __restrict__ carry) {
    int b = blockIdx.x, c = blockIdx.y, t = threadIdx.x;
    int dir = t >> 8, p = t & 255;
    float ar = abar[dir * 512 + 2 * p], ai = abar[dir * 512 + 2 * p + 1];
    float pr = apow[dir * 512 + 2 * p], pi = apow[dir * 512 + 2 * p + 1];
    float sr = 0.f, si = 0.f;
    if (dir == 0) {
        for (int cc = 0; cc < c; ++cc) {
            int o = (b * NC + cc) * 1024 + 2 * p;
            float cr0 = carry[o], ci0 = carry[o + 1];
            float nr = fmaf(pr, sr, fmaf(-pi, si, cr0));
            float ni = fmaf(pr, si, fmaf(pi, sr, ci0));
            sr = nr; si = ni;
        }
    } else {
        for (int cc = NC - 1; cc > c; --cc) {
            int o = (b * NC + cc) * 1024 + 512 + 2 * p;
            float cr0 = carry[o], ci0 = carry[o + 1];
            float nr = fmaf(pr, sr, fmaf(-pi, si, cr0));
            float ni = fmaf(pr, si, fmaf(pi, sr, ci0));
            sr = nr; si = ni;
        }
    }
    ushort_t* base = S + ((size_t)b * SEQ + (size_t)c * CH) * 1024
                       + dir * 512 + 2 * p;
    for (int ii = 0; ii < CH; ++ii) {
        int i = dir ? (CH - 1 - ii) : ii;
        unsigned* addr = (unsigned*)(base + (size_t)i * 1024);
        unsigned u = *addr;
        float re = bf2f((ushort_t)(u & 0xffffu));
        float im = bf2f((ushort_t)(u >> 16));
        float nr = fmaf(ar, sr, fmaf(-ai, si, re));
        float ni = fmaf(ar, si, fmaf(ai, sr, im));
        sr = nr; si = ni;
        *addr = ((unsigned)f2bf(si) << 16) | (unsigned)f2bf(sr);
    }
}

// ---------------------------------------------------------------------------
// ws layout (bytes):
//  SB16 : 0           (67,108,864)  [M][1024] bf16 states both dirs
//  X16  : 67,108,864  (33,554,432)  bf16 x   (live through ALL of GEMM1)
//  Bm16 : 100,663,296 (1,048,576)
//  Cm16 : 101,711,872 (1,048,576)
//  abar : 102,760,448 (4,096)
//  apow : 102,764,544 (4,096)
// d_out scratch (dead until GEMM2 writes y; stream-ordered):
//  carry: d_out + 0         (1,048,576)
//  PW   : d_out + 1,048,576 (12,288)
extern "C" void kernel_launch(void* const* d_in, const int* in_sizes, int n_in,
                              void* d_out, int out_size, void* d_ws, size_t ws_size,
                              hipStream_t stream) {
    const float* x   = (const float*)d_in[0];
    const float* Lre = (const float*)d_in[1];
    const float* Lim = (const float*)d_in[2];
    const float* ldt = (const float*)d_in[3];
    const float* Bre = (const float*)d_in[4];
    const float* Bim = (const float*)d_in[5];
    const float* Cre = (const float*)d_in[6];
    const float* Cim = (const float*)d_in[7];
    const float* Dv  = (const float*)d_in[8];
    float* y = (float*)d_out;
    char* ws = (char*)d_ws;

    ushort_t* SB16 = (ushort_t*)(ws);
    ushort_t* X16  = (ushort_t*)(ws + 67108864);
    ushort_t* Bm16 = (ushort_t*)(ws + 100663296);
    ushort_t* Cm16 = (ushort_t*)(ws + 101711872);
    float* abar  = (float*)(ws + 102760448);
    float* apow  = (float*)(ws + 102764544);
    float* carry = (float*)d_out;                       // dead until GEMM2
    float* PW    = (float*)((char*)d_out + 1048576);    // dead until GEMM2

    prepconv_kernel<<<16384, 256, 0, stream>>>(x, X16, Lre, Lim, ldt,
                                               Bre, Bim, Cre, Cim,
                                               abar, apow, PW, Bm16, Cm16);

    // GEMM1: SB[M][1024] = X16[M][512] * Bm16[1024][512]^T  (+ fused carry)
    gemm_8ph<0, 512, 4><<<512, 512, 0, stream>>>(X16, Bm16, SB16, nullptr,
                                                 nullptr, nullptr, PW, carry);

    dim3 gs(B_SZ, NC);
    scan_fin2<<<gs, 512, 0, stream>>>(SB16, abar, apow, carry);

    // GEMM2: y[M][512] = SB16[M][1024] * Cm16[512][1024]^T + x*(D0+D1)
    gemm_8ph<1, 1024, 2><<<256, 512, 0, stream>>>(SB16, Cm16, nullptr, y,
                                                  x, Dv, nullptr, nullptr);
}